// Round 10
// baseline (113.230 us; speedup 1.0000x reference)
//
#include <hip/hip_runtime.h>
#include <math.h>

// ChamferLoss: pred [32,4096,3] f32, gt [32,4096,3] f32 -> scalar f32.
//
// R14. R13 (main 43.2us, best) profile: harness ws-poison fill = 43us fixed
// floor inside the timed window; main still ~70% idle. VALU-issue floor is
// ~10.7us but busy=18.6us (VGPR_Count=64 vs ~100 live -> AGPR round-trips)
// and only 2 heavyweight blocks/CU -> correlated barrier convoys. R14 makes
// the state fit 64 VGPRs legitimately and quadruples block parallelism:
//  - Block = 128 gt rows x 4096 cols, 8 waves = rw(4) x cq(2), ONE A-frag
//    per wave: live regs = afr(4)+gm(16)+acc(16)+pf(8)+temps ~ 58 <= 64.
//  - LDS 16(sB)+16(sPmin)+1 = 33.3KB -> 4 blocks/CU, grid 1024 = exact
//    4/CU = 32 waves/CU; 4 independent barrier domains hide each other.
//  - T14 async-stage kept (pf regs prefetch next chunk; barrier drains
//    lgkm only) -> small chunks don't re-create R11's drain disease.
//  - Total MFMA + fold VALU work unchanged vs R13 (same pairs, same
//    per-element fold); only the partitioning changed.
//  - __launch_bounds__(512,8) pins the allocator at 64 VGPR.
// Numerics: identical d2-in-MFMA scheme (absmax 0.0 in R11/R12/R13).
//
// Layouts (m74/m101-verified, 32x32x16 bf16):
//   A: row = lane&31, k = 8*(lane>>5)+i
//   B: col = lane&31, k = 8*(lane>>5)+i
//   C: col = lane&31, row = (reg&3) + 8*(reg>>2) + 4*(lane>>5)
// K-slot map (A = -2*gt split h/m, B = pred split h/m):
//   k0-5: Ah*(Bh,Bm)  k6-11: Am*(Bh,Bm)  k12-13: G2h,G2m*1  k14-15: 1*P2h,P2m

typedef short short8 __attribute__((ext_vector_type(8)));
typedef float f32x16 __attribute__((ext_vector_type(16)));
typedef unsigned int uint;

#define NPTS  4096
#define TPBM  512           // 8 waves = rw(4) x cq(2)
#define TPBP  256
#define NPANEL 32           // 128-row gt panels per batch
#define GRID_MAIN (32 * NPANEL)              // 1024
#define NBT   128           // B-tiles per batch (32 cols each)
#define CHT   8             // tiles per cq per chunk (chunk = 16KB)
#define NCH   8             // 64 tiles/cq / CHT
#define ONEB ((short)0x3F80)                 // bf16 1.0

// ---- bf16 split helpers (RNE) ----
__device__ __forceinline__ unsigned short bf16h(float f) {
    uint u = __float_as_uint(f);
    uint r = u + 0x7FFFu + ((u >> 16) & 1u);
    return (unsigned short)(r >> 16);
}
__device__ __forceinline__ float bf16f(unsigned short h) {
    return __uint_as_float(((uint)h) << 16);
}
struct Split2 { unsigned short h, m; };
__device__ __forceinline__ Split2 split2(float x) {
    Split2 s;
    s.h = bf16h(x);
    s.m = bf16h(x - bf16f(s.h));
    return s;
}

// ---- prep: pred -> B-fragments + wspred init (one thread per frag-lane) ----
__global__ __launch_bounds__(TPBP) void chamfer_prep(
    const float* __restrict__ pred, short8* __restrict__ Bfrag,
    uint* __restrict__ wspred)
{
    const int gid = blockIdx.x * TPBP + threadIdx.x;   // 262144 total
    if (gid < 32 * NPTS) wspred[gid] = 0xFFFFFFFFu;    // atomicMin identity

    const int lane = gid & 63;
    const int ent  = gid >> 6;          // b*128 + tile
    const int b    = ent >> 7;
    const int tile = ent & 127;
    const int c31  = lane & 31, half = lane >> 5;

    const float* p = pred + ((size_t)(b * NPTS + tile * 32 + c31)) * 3;
    float x = p[0], y = p[1], z = p[2];
    Split2 X = split2(x), Y = split2(y), Z = split2(z);
    Split2 P2 = split2(fmaf(x, x, fmaf(y, y, z * z)));

    short8 f;
    if (half == 0) {
        f[0]=(short)X.h; f[1]=(short)Y.h; f[2]=(short)Z.h;
        f[3]=(short)X.m; f[4]=(short)Y.m; f[5]=(short)Z.m;
        f[6]=(short)X.h; f[7]=(short)Y.h;
    } else {
        f[0]=(short)Z.h; f[1]=(short)X.m; f[2]=(short)Y.m; f[3]=(short)Z.m;
        f[4]=ONEB;       f[5]=ONEB;       f[6]=(short)P2.h; f[7]=(short)P2.m;
    }
    Bfrag[gid] = f;
}

// ---- main: per block = (batch, 128 gt rows) x all 4096 pred cols ----
__global__ __launch_bounds__(TPBM, 8) void chamfer_mfma(
    const float* __restrict__ gt,
    uint* __restrict__ wspred,
    float* __restrict__ wsgt,
    const short8* __restrict__ Bfrag)
{
    const int bx    = blockIdx.x;      // 1024 = b(32) x panel(32)
    const int b     = bx >> 5;
    const int panel = bx & 31;
    const int tid   = threadIdx.x;
    const int lane  = tid & 63, wid = tid >> 6;
    const int rw    = wid >> 1;        // 0..3: 32-row group
    const int cq    = wid & 1;         // 0..1: 2048-col half
    const int c31   = lane & 31, half = lane >> 5;

    __shared__ short8 sB[2 * CHT * 64];   // 16 KB: [cq][t][lane]
    __shared__ uint   sPmin[NPTS];        // 16 KB: col-mins, uint-ordered
    __shared__ float  sred[128 * 2];      // 1 KB: gt-side [row_local][cq]
    __shared__ float  sw[8];

    for (int c = tid; c < NPTS; c += TPBM) sPmin[c] = 0x7F7FFFFFu;

    // 1 A-frag: rows panel*128 + rw*32 + c31; coords * -2, g2 baked in.
    const float* gtb = gt + (size_t)b * NPTS * 3;
    const int row = panel * 128 + rw * 32 + c31;
    const float* ap = gtb + (size_t)row * 3;
    float x = ap[0], y = ap[1], z = ap[2];
    Split2 X = split2(-2.0f*x), Y = split2(-2.0f*y), Z = split2(-2.0f*z);
    Split2 G2 = split2(fmaf(x, x, fmaf(y, y, z * z)));
    short8 afr;
    if (half == 0) {
        afr[0]=(short)X.h; afr[1]=(short)Y.h; afr[2]=(short)Z.h;
        afr[3]=(short)X.h; afr[4]=(short)Y.h; afr[5]=(short)Z.h;
        afr[6]=(short)X.m; afr[7]=(short)Y.m;
    } else {
        afr[0]=(short)Z.m; afr[1]=(short)X.m; afr[2]=(short)Y.m; afr[3]=(short)Z.m;
        afr[4]=(short)G2.h; afr[5]=(short)G2.m; afr[6]=ONEB; afr[7]=ONEB;
    }

    float gm[16];
#pragma unroll
    for (int r = 0; r < 16; ++r) gm[r] = 1e30f;

    const size_t bfb = (size_t)b * (NBT * 64);
    const f32x16 zero = {0.f,0.f,0.f,0.f,0.f,0.f,0.f,0.f,
                         0.f,0.f,0.f,0.f,0.f,0.f,0.f,0.f};

    // T14 async-stage: pf regs hold the NEXT chunk's 16KB (2 x 16B/thread).
    short8 pf[2];
#pragma unroll
    for (int ps = 0; ps < 2; ++ps) {
        const int u = ps * TPBM + tid;
        const int ucq = u >> 9, ut = (u >> 6) & 7, ul = u & 63;
        pf[ps] = Bfrag[bfb + (size_t)((ucq * 64 + ut) * 64 + ul)];
    }

    for (int ch = 0; ch < NCH; ++ch) {
        __syncthreads();   // sB free (prev reads done); ch=0: init visible
#pragma unroll
        for (int ps = 0; ps < 2; ++ps) sB[ps * TPBM + tid] = pf[ps];
        __syncthreads();   // sB ready (drains lgkm; vmcnt long retired)

        const int chn = (ch + 1 < NCH) ? ch + 1 : ch;   // clamp (no overread)
#pragma unroll
        for (int ps = 0; ps < 2; ++ps) {
            const int u = ps * TPBM + tid;
            const int ucq = u >> 9, ut = (u >> 6) & 7, ul = u & 63;
            pf[ps] = Bfrag[bfb + (size_t)((ucq * 64 + chn * CHT + ut) * 64 + ul)];
        }

#pragma unroll
        for (int t = 0; t < CHT; ++t) {
            short8 bfr = sB[(cq * CHT + t) * 64 + lane];
            f32x16 acc = __builtin_amdgcn_mfma_f32_32x32x16_bf16(
                afr, bfr, zero, 0, 0, 0);

            float pmin = 1e30f;
#pragma unroll
            for (int r = 0; r < 16; r += 2) {
                gm[r]   = fminf(gm[r],   acc[r]);             // gt row-mins
                gm[r+1] = fminf(gm[r+1], acc[r+1]);
                pmin = fminf(fminf(acc[r], acc[r+1]), pmin);  // v_min3
            }
            // this lane's 32-row col-min -> LDS atomic folds halves + rw waves
            atomicMin(&sPmin[cq * 2048 + (ch * CHT + t) * 32 + c31],
                      __float_as_uint(fmaxf(pmin, 1e-12f)));
        }
    }
    __syncthreads();   // sPmin complete

    // pred-side epilogue: batched guarded atomicMin, coalesced
    uint* wsb = wspred + (size_t)b * NPTS;
    for (int c = tid; c < NPTS; c += TPBM) {
        const uint mine = sPmin[c];
        if (mine < wsb[c]) atomicMin(&wsb[c], mine);
    }

    // gt-side: fold row-mins across the 32 cols (c31 lanes, within half)
#pragma unroll
    for (int off = 1; off < 32; off <<= 1)
#pragma unroll
        for (int r = 0; r < 16; ++r)
            gm[r] = fminf(gm[r], __shfl_xor(gm[r], off, 64));
    if (c31 == 0) {   // lanes 0 and 32 (half 0/1) hold disjoint rows
#pragma unroll
        for (int r = 0; r < 16; ++r)
            sred[(rw*32 + (r&3) + 8*(r>>2) + 4*half) * 2 + cq] = gm[r];
    }
    __syncthreads();

    float ssum = 0.0f;
    if (tid < 128) {   // 128 rows: fold 2 cq, sqrt
        float v = fminf(sred[tid * 2], sred[tid * 2 + 1]);
        ssum = sqrtf(fmaxf(v, 1e-12f));
    }
#pragma unroll
    for (int off = 32; off > 0; off >>= 1) ssum += __shfl_down(ssum, off, 64);
    if (lane == 0) sw[wid] = ssum;
    __syncthreads();
    if (tid == 0)
        wsgt[bx] = sw[0]+sw[1]+sw[2]+sw[3]+sw[4]+sw[5]+sw[6]+sw[7];
}

// ---- finish: sum sqrt(pred mins) + gt partials -> out ----
__global__ __launch_bounds__(TPBP) void chamfer_finish(
    const uint* __restrict__ wspred, const float* __restrict__ wsgt,
    float* __restrict__ out)
{
    __shared__ float swv[TPBP / 64];
    const int tid  = threadIdx.x;
    const int base = blockIdx.x * (TPBP * 4) + tid;   // 128 blocks x 1024

    float s = 0.0f;
#pragma unroll
    for (int r = 0; r < 4; ++r)
        s += sqrtf(__uint_as_float(wspred[base + r * TPBP]));
    if (blockIdx.x == 0) {
#pragma unroll
        for (int r = 0; r < 4; ++r)
            s += wsgt[tid + r * TPBP];   // 1024 per-block gt partials
    }

#pragma unroll
    for (int off = 32; off > 0; off >>= 1) s += __shfl_down(s, off, 64);
    const int wid = tid >> 6, lane = tid & 63;
    if (lane == 0) swv[wid] = s;
    __syncthreads();
    if (tid == 0) {
        float tot = swv[0] + swv[1] + swv[2] + swv[3];
        atomicAdd(out, tot * (1.0f / 131072.0f));
    }
}

extern "C" void kernel_launch(void* const* d_in, const int* in_sizes, int n_in,
                              void* d_out, int out_size, void* d_ws, size_t ws_size,
                              hipStream_t stream)
{
    const float* pred = (const float*)d_in[0];
    const float* gt   = (const float*)d_in[1];
    float* out        = (float*)d_out;

    // ws layout: [0,512K) wspred uints; [512K,+4K) wsgt; [1M,5M) Bfrag
    uint*   wspred = (uint*)d_ws;
    float*  wsgt   = (float*)((char*)d_ws + (512 << 10));
    short8* Bfrag  = (short8*)((char*)d_ws + (1 << 20));

    hipMemsetAsync(d_out, 0, sizeof(float), stream);

    chamfer_prep<<<dim3((32 * NBT * 64) / TPBP), dim3(TPBP), 0, stream>>>(
        pred, Bfrag, wspred);
    chamfer_mfma<<<dim3(GRID_MAIN), dim3(TPBM), 0, stream>>>(
        gt, wspred, wsgt, Bfrag);
    chamfer_finish<<<dim3(128), dim3(TPBP), 0, stream>>>(wspred, wsgt, out);
}

// Round 11
// 105.819 us; speedup vs baseline: 1.0700x; 1.0700x over previous
//
#include <hip/hip_runtime.h>
#include <math.h>

// ChamferLoss: pred [32,4096,3] f32, gt [32,4096,3] f32 -> scalar f32.
//
// R15: TWO-PASS MFMA. R14 post-mortem: VGPR_Count=32 vs (512,8) cap 64 ->
// allocator moved acc/gm to AGPRs, every fold pays v_accvgpr_read (VALU
// busy 19.9us vs 11us floor); 1 MFMA/ds_read re-created R11's drain.
// Structural step: the pred-side cross-block merge (wspred atomics + init
// + sPmin LDS atomics + min3 tree + 128-block finish) exists ONLY because
// one pass computes both chamfer directions. Two passes (dir0: A=gt rows
// stream pred-frags; dir1: A=pred rows stream gt-frags) delete ALL of it:
//  - block owns 512 query rows; fold = 16 v_min per MFMA (1 min/pair,
//    the hard VALU floor ~14us); one plain float store per block.
//  - 2x MFMA count, but MFMA busy only 1.7->3.4us (trivial per profile).
//  - 2 A-frags/wave (R13-proven density): 2 MFMA per 1KB ds_read ->
//    LDS-unit traffic 2MB/CU ~ 10us, hidden under the VALU fold.
//  - __launch_bounds__(512,4): cap 128 >= ~90 live -> no AGPR round-trips.
//  - grid 512 = dir(2) x b(32) x panel(8), exactly 2 blocks/CU (R13 shape).
//  - T14 async-stage kept: pf regs prefetch next 32KB chunk, barriers
//    drain lgkm only. No overread (chunk index clamped).
//  - prep builds B-form frags for BOTH sides (8MB); no wspred init.
//  - finish: 1 block sums 512 partials -> out[0] (no atomics, no memset).
// Numerics per direction identical to R11-R14 (absmax 0.0 x4).
//
// Layouts (m74/m101-verified, 32x32x16 bf16):
//   A: row = lane&31, k = 8*(lane>>5)+i
//   B: col = lane&31, k = 8*(lane>>5)+i
//   C: col = lane&31, row = (reg&3) + 8*(reg>>2) + 4*(lane>>5)
// K-slot map (A = -2*query split h/m, B = target split h/m):
//   k0-5: Ah*(Bh,Bm)  k6-11: Am*(Bh,Bm)  k12-13: Q2h,Q2m*1  k14-15: 1*T2h,T2m
//   => acc = d2 = q2 + t2 - 2*dot directly.

typedef short short8 __attribute__((ext_vector_type(8)));
typedef float f32x16 __attribute__((ext_vector_type(16)));
typedef unsigned int uint;

#define NPTS  4096
#define TPBM  512           // 8 waves, each owns 64 rows (2 A-frags)
#define TPBP  256
#define NPANEL 8            // 512-row query panels
#define GRID_MAIN (2 * 32 * NPANEL)          // 512
#define NBT   128           // B-tiles per (side,batch), 32 cols each
#define CHT   32            // tiles per chunk (full-share) = 32KB
#define NCH   4             // 128 / 32
#define ONEB ((short)0x3F80)                 // bf16 1.0

// ---- bf16 split helpers (RNE) ----
__device__ __forceinline__ unsigned short bf16h(float f) {
    uint u = __float_as_uint(f);
    uint r = u + 0x7FFFu + ((u >> 16) & 1u);
    return (unsigned short)(r >> 16);
}
__device__ __forceinline__ float bf16f(unsigned short h) {
    return __uint_as_float(((uint)h) << 16);
}
struct Split2 { unsigned short h, m; };
__device__ __forceinline__ Split2 split2(float x) {
    Split2 s;
    s.h = bf16h(x);
    s.m = bf16h(x - bf16f(s.h));
    return s;
}

// ---- prep: BOTH sides -> B-form fragments (one thread per frag-lane) ----
// Bfrag layout: [side(2)][b(32)][tile(128)][lane(64)], side0=pred, side1=gt.
__global__ __launch_bounds__(TPBP) void chamfer_prep(
    const float* __restrict__ pred, const float* __restrict__ gt,
    short8* __restrict__ Bfrag)
{
    const int gid  = blockIdx.x * TPBP + threadIdx.x;   // 524288 total
    const int lane = gid & 63;
    const int ent  = gid >> 6;          // side*4096 + b*128 + tile
    const int side = ent >> 12;
    const int b    = (ent >> 7) & 31;
    const int tile = ent & 127;
    const int c31  = lane & 31, half = lane >> 5;

    const float* src = side ? gt : pred;
    const float* p = src + ((size_t)(b * NPTS + tile * 32 + c31)) * 3;
    float x = p[0], y = p[1], z = p[2];
    Split2 X = split2(x), Y = split2(y), Z = split2(z);
    Split2 T2 = split2(fmaf(x, x, fmaf(y, y, z * z)));

    short8 f;
    if (half == 0) {
        f[0]=(short)X.h; f[1]=(short)Y.h; f[2]=(short)Z.h;
        f[3]=(short)X.m; f[4]=(short)Y.m; f[5]=(short)Z.m;
        f[6]=(short)X.h; f[7]=(short)Y.h;
    } else {
        f[0]=(short)Z.h; f[1]=(short)X.m; f[2]=(short)Y.m; f[3]=(short)Z.m;
        f[4]=ONEB;       f[5]=ONEB;       f[6]=(short)T2.h; f[7]=(short)T2.m;
    }
    Bfrag[gid] = f;
}

// ---- main: block = (dir, batch, 512 query rows) x all 4096 target cols ----
__global__ __launch_bounds__(TPBM, 4) void chamfer_mfma(
    const float* __restrict__ pred,
    const float* __restrict__ gt,
    float* __restrict__ wsgt,
    const short8* __restrict__ Bfrag)
{
    const int bx    = blockIdx.x;      // 512 = dir(2) x b(32) x panel(8)
    const int dir   = bx >> 8;
    const int rem   = bx & 255;
    const int b     = rem >> 3;
    const int panel = rem & 7;
    const int tid   = threadIdx.x;
    const int lane  = tid & 63, wid = tid >> 6;
    const int c31   = lane & 31, half = lane >> 5;

    __shared__ short8 sB[CHT * 64];   // 32 KB, shared by all 8 waves
    __shared__ float  sw[8];

    // dir0: queries = gt rows, targets = pred (side0 frags)
    // dir1: queries = pred rows, targets = gt  (side1 frags)
    const float* qsrc = (dir ? pred : gt) + (size_t)b * NPTS * 3;
    const size_t bfb  = ((size_t)dir * 32 + b) * (NBT * 64);

    // 2 A-frags: rows panel*512 + wid*64 + fr*32 + c31; -2*coords, q2 baked.
    short8 afr[2];
    float gm[2][16];
#pragma unroll
    for (int fr = 0; fr < 2; ++fr) {
        const int row = panel * 512 + wid * 64 + fr * 32 + c31;
        const float* ap = qsrc + (size_t)row * 3;
        float x = ap[0], y = ap[1], z = ap[2];
        Split2 X = split2(-2.0f*x), Y = split2(-2.0f*y), Z = split2(-2.0f*z);
        Split2 Q2 = split2(fmaf(x, x, fmaf(y, y, z * z)));
        short8 a;
        if (half == 0) {
            a[0]=(short)X.h; a[1]=(short)Y.h; a[2]=(short)Z.h;
            a[3]=(short)X.h; a[4]=(short)Y.h; a[5]=(short)Z.h;
            a[6]=(short)X.m; a[7]=(short)Y.m;
        } else {
            a[0]=(short)Z.m; a[1]=(short)X.m; a[2]=(short)Y.m; a[3]=(short)Z.m;
            a[4]=(short)Q2.h; a[5]=(short)Q2.m; a[6]=ONEB; a[7]=ONEB;
        }
        afr[fr] = a;
#pragma unroll
        for (int r = 0; r < 16; ++r) gm[fr][r] = 1e30f;
    }

    const f32x16 zero = {0.f,0.f,0.f,0.f,0.f,0.f,0.f,0.f,
                         0.f,0.f,0.f,0.f,0.f,0.f,0.f,0.f};

    // T14 async-stage: pf holds the NEXT 32KB chunk (4 x 16B per thread).
    short8 pf[4];
#pragma unroll
    for (int ps = 0; ps < 4; ++ps) {
        const int u = ps * TPBM + tid;
        pf[ps] = Bfrag[bfb + (size_t)u];   // chunk 0: tiles 0..31 contiguous
    }

    for (int ch = 0; ch < NCH; ++ch) {
        __syncthreads();   // prior chunk's reads done
#pragma unroll
        for (int ps = 0; ps < 4; ++ps) sB[ps * TPBM + tid] = pf[ps];
        __syncthreads();   // sB visible (lgkm drain only; vmcnt retired)

        const int chn = (ch + 1 < NCH) ? ch + 1 : ch;   // clamp: no overread
#pragma unroll
        for (int ps = 0; ps < 4; ++ps) {
            const int u = ps * TPBM + tid;
            pf[ps] = Bfrag[bfb + (size_t)(chn * (CHT * 64) + u)];
        }

        // 32 tiles: per tile 1 ds_read_b128 + 2 MFMA + 32 v_min
#pragma unroll 4
        for (int t = 0; t < CHT; ++t) {
            short8 bfr = sB[t * 64 + lane];
            f32x16 a0 = __builtin_amdgcn_mfma_f32_32x32x16_bf16(
                afr[0], bfr, zero, 0, 0, 0);
            f32x16 a1 = __builtin_amdgcn_mfma_f32_32x32x16_bf16(
                afr[1], bfr, zero, 0, 0, 0);
#pragma unroll
            for (int r = 0; r < 16; ++r) {
                gm[0][r] = fminf(gm[0][r], a0[r]);
                gm[1][r] = fminf(gm[1][r], a1[r]);
            }
        }
    }

    // Epilogue: fold row-mins across the 32 target-cols (c31 lanes).
#pragma unroll
    for (int off = 1; off < 32; off <<= 1)
#pragma unroll
        for (int fr = 0; fr < 2; ++fr)
#pragma unroll
            for (int r = 0; r < 16; ++r)
                gm[fr][r] = fminf(gm[fr][r], __shfl_xor(gm[fr][r], off, 64));

    // lanes 0 and 32 hold complete mins for 2x16 disjoint rows each
    float s = 0.0f;
    if (c31 == 0) {
#pragma unroll
        for (int fr = 0; fr < 2; ++fr)
#pragma unroll
            for (int r = 0; r < 16; ++r)
                s += sqrtf(fmaxf(gm[fr][r], 1e-12f));
    }
    s += __shfl_xor(s, 32, 64);   // combine halves
    if (lane == 0) sw[wid] = s;
    __syncthreads();
    if (tid == 0)
        wsgt[bx] = sw[0]+sw[1]+sw[2]+sw[3]+sw[4]+sw[5]+sw[6]+sw[7];
}

// ---- finish: one block sums the 512 per-block partials -> out[0] ----
__global__ __launch_bounds__(TPBP) void chamfer_finish(
    const float* __restrict__ wsgt, float* __restrict__ out)
{
    __shared__ float swv[TPBP / 64];
    const int tid = threadIdx.x;

    float s = 0.0f;
#pragma unroll
    for (int r = 0; r < GRID_MAIN / TPBP; ++r)
        s += wsgt[tid + r * TPBP];

#pragma unroll
    for (int off = 32; off > 0; off >>= 1) s += __shfl_down(s, off, 64);
    const int wid = tid >> 6, lane = tid & 63;
    if (lane == 0) swv[wid] = s;
    __syncthreads();
    if (tid == 0)
        out[0] = (swv[0] + swv[1] + swv[2] + swv[3]) * (1.0f / 131072.0f);
}

extern "C" void kernel_launch(void* const* d_in, const int* in_sizes, int n_in,
                              void* d_out, int out_size, void* d_ws, size_t ws_size,
                              hipStream_t stream)
{
    const float* pred = (const float*)d_in[0];
    const float* gt   = (const float*)d_in[1];
    float* out        = (float*)d_out;

    // ws layout: [0,2K) wsgt floats; [1M,9M) Bfrag (both sides)
    float*  wsgt  = (float*)d_ws;
    short8* Bfrag = (short8*)((char*)d_ws + (1 << 20));

    chamfer_prep<<<dim3((2 * 32 * NBT * 64) / TPBP), dim3(TPBP), 0, stream>>>(
        pred, gt, Bfrag);
    chamfer_mfma<<<dim3(GRID_MAIN), dim3(TPBM), 0, stream>>>(
        pred, gt, wsgt, Bfrag);
    chamfer_finish<<<dim3(1), dim3(TPBP), 0, stream>>>(wsgt, out);
}

// Round 13
// 104.254 us; speedup vs baseline: 1.0861x; 1.0150x over previous
//
#include <hip/hip_runtime.h>
#include <math.h>

// ChamferLoss: pred [32,4096,3] f32, gt [32,4096,3] f32 -> scalar f32.
//
// R16 = R15 (two-pass MFMA, clean merge-free structure, main 45.6us) with
// the two measured idle sources removed. R15 counters: MFMA busy 13.3us
// (= full-rate: 1.05M issues x 32cy/SIMD), VALU 22us, wall 45.6 -> ~50%
// idle at occupancy 29.6% (2 heavyweight 8-wave blocks/CU, correlated
// barrier convoys) and un-paired fold (32 fmin/tile).
//  - v_min3 FOLD PAIRING: tiles processed 2 at a time;
//    gm[r] = min3(acc_t0[r], acc_t1[r], gm[r]) -> fold insts halve
//    (13.7us -> 6.8us of VALU).
//  - TPB 256 (4 waves x 64 rows = 256-row block), grid 1024 = exactly
//    4 blocks/CU; LDS 8.2KB; 4 independent barrier domains per CU.
//  - CHT=8 (8KB chunks, pf[2], NCH=16): T14 async-stage kept -> barrier
//    drains lgkm only; registers ~110 under the (256,4) 128-VGPR cap.
//  - d_out memset dropped (finish plain-stores out[0]).
// Numerics per direction identical to R11-R15 (absmax 0.0 x5).
// (R17 resubmit: R16 bench died to container infra failure, no counters;
//  re-running the same experiment rather than mutating blind.)
//
// Layouts (m74/m101-verified, 32x32x16 bf16):
//   A: row = lane&31, k = 8*(lane>>5)+i
//   B: col = lane&31, k = 8*(lane>>5)+i
//   C: col = lane&31, row = (reg&3) + 8*(reg>>2) + 4*(lane>>5)
// K-slot map (A = -2*query split h/m, B = target split h/m):
//   k0-5: Ah*(Bh,Bm)  k6-11: Am*(Bh,Bm)  k12-13: Q2h,Q2m*1  k14-15: 1*T2h,T2m
//   => acc = d2 = q2 + t2 - 2*dot directly.

typedef short short8 __attribute__((ext_vector_type(8)));
typedef float f32x16 __attribute__((ext_vector_type(16)));
typedef unsigned int uint;

#define NPTS  4096
#define TPBM  256           // 4 waves, each owns 64 rows (2 A-frags)
#define TPBP  256
#define NPANEL 16           // 256-row query panels
#define GRID_MAIN (2 * 32 * NPANEL)          // 1024 = 4 blocks/CU exactly
#define NBT   128           // B-tiles per (side,batch), 32 cols each
#define CHT   8             // tiles per chunk = 8KB
#define NCH   16            // 128 / 8
#define ONEB ((short)0x3F80)                 // bf16 1.0

// ---- bf16 split helpers (RNE) ----
__device__ __forceinline__ unsigned short bf16h(float f) {
    uint u = __float_as_uint(f);
    uint r = u + 0x7FFFu + ((u >> 16) & 1u);
    return (unsigned short)(r >> 16);
}
__device__ __forceinline__ float bf16f(unsigned short h) {
    return __uint_as_float(((uint)h) << 16);
}
struct Split2 { unsigned short h, m; };
__device__ __forceinline__ Split2 split2(float x) {
    Split2 s;
    s.h = bf16h(x);
    s.m = bf16h(x - bf16f(s.h));
    return s;
}

// ---- prep: BOTH sides -> B-form fragments (one thread per frag-lane) ----
// Bfrag layout: [side(2)][b(32)][tile(128)][lane(64)], side0=pred, side1=gt.
__global__ __launch_bounds__(TPBP) void chamfer_prep(
    const float* __restrict__ pred, const float* __restrict__ gt,
    short8* __restrict__ Bfrag)
{
    const int gid  = blockIdx.x * TPBP + threadIdx.x;   // 524288 total
    const int lane = gid & 63;
    const int ent  = gid >> 6;          // side*4096 + b*128 + tile
    const int side = ent >> 12;
    const int b    = (ent >> 7) & 31;
    const int tile = ent & 127;
    const int c31  = lane & 31, half = lane >> 5;

    const float* src = side ? gt : pred;
    const float* p = src + ((size_t)(b * NPTS + tile * 32 + c31)) * 3;
    float x = p[0], y = p[1], z = p[2];
    Split2 X = split2(x), Y = split2(y), Z = split2(z);
    Split2 T2 = split2(fmaf(x, x, fmaf(y, y, z * z)));

    short8 f;
    if (half == 0) {
        f[0]=(short)X.h; f[1]=(short)Y.h; f[2]=(short)Z.h;
        f[3]=(short)X.m; f[4]=(short)Y.m; f[5]=(short)Z.m;
        f[6]=(short)X.h; f[7]=(short)Y.h;
    } else {
        f[0]=(short)Z.h; f[1]=(short)X.m; f[2]=(short)Y.m; f[3]=(short)Z.m;
        f[4]=ONEB;       f[5]=ONEB;       f[6]=(short)T2.h; f[7]=(short)T2.m;
    }
    Bfrag[gid] = f;
}

// ---- main: block = (dir, batch, 256 query rows) x all 4096 target cols ----
__global__ __launch_bounds__(TPBM, 4) void chamfer_mfma(
    const float* __restrict__ pred,
    const float* __restrict__ gt,
    float* __restrict__ wsgt,
    const short8* __restrict__ Bfrag)
{
    const int bx    = blockIdx.x;      // 1024 = dir(2) x b(32) x panel(16)
    const int dir   = bx >> 9;
    const int rem   = bx & 511;
    const int b     = rem >> 4;
    const int panel = rem & 15;
    const int tid   = threadIdx.x;
    const int lane  = tid & 63, wid = tid >> 6;
    const int c31   = lane & 31, half = lane >> 5;

    __shared__ short8 sB[CHT * 64];   // 8 KB, shared by the 4 waves
    __shared__ float  sw[4];

    // dir0: queries = gt rows, targets = pred (side0 frags)
    // dir1: queries = pred rows, targets = gt  (side1 frags)
    const float* qsrc = (dir ? pred : gt) + (size_t)b * NPTS * 3;
    const size_t bfb  = ((size_t)dir * 32 + b) * (NBT * 64);

    // 2 A-frags: rows panel*256 + wid*64 + fr*32 + c31; -2*coords, q2 baked.
    short8 afr[2];
    float gm[2][16];
#pragma unroll
    for (int fr = 0; fr < 2; ++fr) {
        const int row = panel * 256 + wid * 64 + fr * 32 + c31;
        const float* ap = qsrc + (size_t)row * 3;
        float x = ap[0], y = ap[1], z = ap[2];
        Split2 X = split2(-2.0f*x), Y = split2(-2.0f*y), Z = split2(-2.0f*z);
        Split2 Q2 = split2(fmaf(x, x, fmaf(y, y, z * z)));
        short8 a;
        if (half == 0) {
            a[0]=(short)X.h; a[1]=(short)Y.h; a[2]=(short)Z.h;
            a[3]=(short)X.h; a[4]=(short)Y.h; a[5]=(short)Z.h;
            a[6]=(short)X.m; a[7]=(short)Y.m;
        } else {
            a[0]=(short)Z.m; a[1]=(short)X.m; a[2]=(short)Y.m; a[3]=(short)Z.m;
            a[4]=(short)Q2.h; a[5]=(short)Q2.m; a[6]=ONEB; a[7]=ONEB;
        }
        afr[fr] = a;
#pragma unroll
        for (int r = 0; r < 16; ++r) gm[fr][r] = 1e30f;
    }

    const f32x16 zero = {0.f,0.f,0.f,0.f,0.f,0.f,0.f,0.f,
                         0.f,0.f,0.f,0.f,0.f,0.f,0.f,0.f};

    // T14 async-stage: pf holds the NEXT 8KB chunk (2 x 16B per thread).
    short8 pf[2];
#pragma unroll
    for (int ps = 0; ps < 2; ++ps)
        pf[ps] = Bfrag[bfb + (size_t)(ps * TPBM + tid)];

    for (int ch = 0; ch < NCH; ++ch) {
        __syncthreads();   // prior chunk's reads done
#pragma unroll
        for (int ps = 0; ps < 2; ++ps) sB[ps * TPBM + tid] = pf[ps];
        __syncthreads();   // sB visible (lgkm drain only; vmcnt retired)

        const int chn = (ch + 1 < NCH) ? ch + 1 : ch;   // clamp: no overread
#pragma unroll
        for (int ps = 0; ps < 2; ++ps)
            pf[ps] = Bfrag[bfb + (size_t)(chn * (CHT * 64) + ps * TPBM + tid)];

        // tiles in PAIRS: per pair 2 ds_read + 4 MFMA + 32 v_min3
#pragma unroll
        for (int tp = 0; tp < CHT / 2; ++tp) {
            short8 b0 = sB[(2 * tp) * 64 + lane];
            short8 b1 = sB[(2 * tp + 1) * 64 + lane];
            f32x16 a00 = __builtin_amdgcn_mfma_f32_32x32x16_bf16(
                afr[0], b0, zero, 0, 0, 0);
            f32x16 a01 = __builtin_amdgcn_mfma_f32_32x32x16_bf16(
                afr[0], b1, zero, 0, 0, 0);
#pragma unroll
            for (int r = 0; r < 16; ++r)
                gm[0][r] = fminf(fminf(a00[r], a01[r]), gm[0][r]);  // v_min3
            f32x16 a10 = __builtin_amdgcn_mfma_f32_32x32x16_bf16(
                afr[1], b0, zero, 0, 0, 0);
            f32x16 a11 = __builtin_amdgcn_mfma_f32_32x32x16_bf16(
                afr[1], b1, zero, 0, 0, 0);
#pragma unroll
            for (int r = 0; r < 16; ++r)
                gm[1][r] = fminf(fminf(a10[r], a11[r]), gm[1][r]);  // v_min3
        }
    }

    // Epilogue: fold row-mins across the 32 target-cols (c31 lanes).
#pragma unroll
    for (int off = 1; off < 32; off <<= 1)
#pragma unroll
        for (int fr = 0; fr < 2; ++fr)
#pragma unroll
            for (int r = 0; r < 16; ++r)
                gm[fr][r] = fminf(gm[fr][r], __shfl_xor(gm[fr][r], off, 64));

    // lanes 0 and 32 hold complete mins for 2x16 disjoint rows each
    float s = 0.0f;
    if (c31 == 0) {
#pragma unroll
        for (int fr = 0; fr < 2; ++fr)
#pragma unroll
            for (int r = 0; r < 16; ++r)
                s += sqrtf(fmaxf(gm[fr][r], 1e-12f));
    }
    s += __shfl_xor(s, 32, 64);   // combine halves
    if (lane == 0) sw[wid] = s;
    __syncthreads();
    if (tid == 0)
        wsgt[bx] = sw[0] + sw[1] + sw[2] + sw[3];
}

// ---- finish: one block sums the 1024 per-block partials -> out[0] ----
__global__ __launch_bounds__(TPBP) void chamfer_finish(
    const float* __restrict__ wsgt, float* __restrict__ out)
{
    __shared__ float swv[TPBP / 64];
    const int tid = threadIdx.x;

    float s = 0.0f;
#pragma unroll
    for (int r = 0; r < GRID_MAIN / TPBP; ++r)
        s += wsgt[tid + r * TPBP];

#pragma unroll
    for (int off = 32; off > 0; off >>= 1) s += __shfl_down(s, off, 64);
    const int wid = tid >> 6, lane = tid & 63;
    if (lane == 0) swv[wid] = s;
    __syncthreads();
    if (tid == 0)
        out[0] = (swv[0] + swv[1] + swv[2] + swv[3]) * (1.0f / 131072.0f);
}

extern "C" void kernel_launch(void* const* d_in, const int* in_sizes, int n_in,
                              void* d_out, int out_size, void* d_ws, size_t ws_size,
                              hipStream_t stream)
{
    const float* pred = (const float*)d_in[0];
    const float* gt   = (const float*)d_in[1];
    float* out        = (float*)d_out;

    // ws layout: [0,4K) wsgt floats; [1M,9M) Bfrag (both sides)
    float*  wsgt  = (float*)d_ws;
    short8* Bfrag = (short8*)((char*)d_ws + (1 << 20));

    chamfer_prep<<<dim3((2 * 32 * NBT * 64) / TPBP), dim3(TPBP), 0, stream>>>(
        pred, gt, Bfrag);
    chamfer_mfma<<<dim3(GRID_MAIN), dim3(TPBM), 0, stream>>>(
        pred, gt, wsgt, Bfrag);
    chamfer_finish<<<dim3(1), dim3(TPBP), 0, stream>>>(wsgt, out);
}

// Round 15
// 97.839 us; speedup vs baseline: 1.1573x; 1.0656x over previous
//
#include <hip/hip_runtime.h>
#include <math.h>

// ChamferLoss: pred [32,4096,3] f32, gt [32,4096,3] f32 -> scalar f32.
//
// R19 = R15 EXACTLY (two-pass MFMA, 8-wave blocks, grid 512, CHT=32, T14
// async-stage, fminf fold; main 45.6us, absmax 0.0) + ONE structural change:
// chamfer_prep is DELETED. Staging loads raw target coords (12B/entry, 3MB
// total -> L2-resident) and builds the bf16-split fragments in registers
// before the ds_write (~30 VALU x 4 entries/thread/chunk ~ 0.8us aggregate).
// Removes: prep kernel (~6us) + its launch gap + 8MB Bfrag ws traffic.
//
// R18 post-mortem: inline-asm v_min3_f32 reading MFMA dsts corrupted results
// (absmax 0.074) -- the MAI->VALU hazard recognizer doesn't cover INLINEASM
// consumers, so stale-register reads lowered the mins. Fold stays fminf
// (R16 showed pairing/fusion gains ~0 anyway; fold lever dead until disasm).
//
// Layouts (m74/m101-verified, 32x32x16 bf16):
//   A: row = lane&31, k = 8*(lane>>5)+i
//   B: col = lane&31, k = 8*(lane>>5)+i
//   C: col = lane&31, row = (reg&3) + 8*(reg>>2) + 4*(lane>>5)
// K-slot map (A = -2*query split h/m, B = target split h/m):
//   k0-5: Ah*(Bh,Bm)  k6-11: Am*(Bh,Bm)  k12-13: Q2h,Q2m*1  k14-15: 1*T2h,T2m
//   => acc = d2 = q2 + t2 - 2*dot directly.  (absmax 0.0 in R11-R17)

typedef short short8 __attribute__((ext_vector_type(8)));
typedef float f32x16 __attribute__((ext_vector_type(16)));
typedef unsigned int uint;

#define NPTS  4096
#define TPBM  512           // 8 waves, each owns 64 rows (2 A-frags)
#define TPBP  256
#define NPANEL 8            // 512-row query panels
#define GRID_MAIN (2 * 32 * NPANEL)          // 512
#define CHT   32            // tiles per chunk (32 cols each) = 32KB staged
#define NCH   4             // 128 tiles total per (dir,batch)
#define ONEB ((short)0x3F80)                 // bf16 1.0

// ---- bf16 split helpers (RNE) ----
__device__ __forceinline__ unsigned short bf16h(float f) {
    uint u = __float_as_uint(f);
    uint r = u + 0x7FFFu + ((u >> 16) & 1u);
    return (unsigned short)(r >> 16);
}
__device__ __forceinline__ float bf16f(unsigned short h) {
    return __uint_as_float(((uint)h) << 16);
}
struct Split2 { unsigned short h, m; };
__device__ __forceinline__ Split2 split2(float x) {
    Split2 s;
    s.h = bf16h(x);
    s.m = bf16h(x - bf16f(s.h));
    return s;
}

// ---- main: block = (dir, batch, 512 query rows) x all 4096 target cols ----
__global__ __launch_bounds__(TPBM, 4) void chamfer_mfma(
    const float* __restrict__ pred,
    const float* __restrict__ gt,
    float* __restrict__ wsgt)
{
    const int bx    = blockIdx.x;      // 512 = dir(2) x b(32) x panel(8)
    const int dir   = bx >> 8;
    const int rem   = bx & 255;
    const int b     = rem >> 3;
    const int panel = rem & 7;
    const int tid   = threadIdx.x;
    const int lane  = tid & 63, wid = tid >> 6;
    const int c31   = lane & 31, half = lane >> 5;

    __shared__ short8 sB[CHT * 64];   // 32 KB, shared by all 8 waves
    __shared__ float  sw[8];

    // dir0: queries = gt rows, targets = pred; dir1: queries = pred, targets = gt
    const float* qsrc = (dir ? pred : gt) + (size_t)b * NPTS * 3;
    const float* tsrc = (dir ? gt : pred) + (size_t)b * NPTS * 3;

    // 2 A-frags: rows panel*512 + wid*64 + fr*32 + c31; -2*coords, q2 baked.
    short8 afr[2];
    float gm[2][16];
#pragma unroll
    for (int fr = 0; fr < 2; ++fr) {
        const int row = panel * 512 + wid * 64 + fr * 32 + c31;
        const float* ap = qsrc + (size_t)row * 3;
        float x = ap[0], y = ap[1], z = ap[2];
        Split2 X = split2(-2.0f*x), Y = split2(-2.0f*y), Z = split2(-2.0f*z);
        Split2 Q2 = split2(fmaf(x, x, fmaf(y, y, z * z)));
        short8 a;
        if (half == 0) {
            a[0]=(short)X.h; a[1]=(short)Y.h; a[2]=(short)Z.h;
            a[3]=(short)X.h; a[4]=(short)Y.h; a[5]=(short)Z.h;
            a[6]=(short)X.m; a[7]=(short)Y.m;
        } else {
            a[0]=(short)Z.m; a[1]=(short)X.m; a[2]=(short)Y.m; a[3]=(short)Z.m;
            a[4]=(short)Q2.h; a[5]=(short)Q2.m; a[6]=ONEB; a[7]=ONEB;
        }
        afr[fr] = a;
#pragma unroll
        for (int r = 0; r < 16; ++r) gm[fr][r] = 1e30f;
    }

    const f32x16 zero = {0.f,0.f,0.f,0.f,0.f,0.f,0.f,0.f,
                         0.f,0.f,0.f,0.f,0.f,0.f,0.f,0.f};

    // T14 async-stage, raw form: rx/ry/rz hold the NEXT chunk's coords.
    // Entry u = ps*TPBM+tid: tile u>>6, frag-lane u&63, point col u&31,
    // frag half (u>>5)&1. Both halves load the same point (L1 dedupes).
    float rx[4], ry[4], rz[4];
#pragma unroll
    for (int ps = 0; ps < 4; ++ps) {
        const int u  = ps * TPBM + tid;
        const int pt = (u >> 6) * 32 + (u & 31);     // chunk 0
        const float* p = tsrc + (size_t)pt * 3;
        rx[ps] = p[0]; ry[ps] = p[1]; rz[ps] = p[2];
    }

    for (int ch = 0; ch < NCH; ++ch) {
        __syncthreads();   // prior chunk's reads done
        // build fragments in-register, write to LDS (replaces prep kernel)
#pragma unroll
        for (int ps = 0; ps < 4; ++ps) {
            const int u = ps * TPBM + tid;
            float x = rx[ps], y = ry[ps], z = rz[ps];
            Split2 X = split2(x), Y = split2(y), Z = split2(z);
            short8 f;
            if (((u >> 5) & 1) == 0) {
                f[0]=(short)X.h; f[1]=(short)Y.h; f[2]=(short)Z.h;
                f[3]=(short)X.m; f[4]=(short)Y.m; f[5]=(short)Z.m;
                f[6]=(short)X.h; f[7]=(short)Y.h;
            } else {
                Split2 T2 = split2(fmaf(x, x, fmaf(y, y, z * z)));
                f[0]=(short)Z.h; f[1]=(short)X.m; f[2]=(short)Y.m;
                f[3]=(short)Z.m; f[4]=ONEB; f[5]=ONEB;
                f[6]=(short)T2.h; f[7]=(short)T2.m;
            }
            sB[u] = f;
        }
        __syncthreads();   // sB visible

        const int chn = (ch + 1 < NCH) ? ch + 1 : ch;   // clamp: no overread
#pragma unroll
        for (int ps = 0; ps < 4; ++ps) {
            const int u  = ps * TPBM + tid;
            const int pt = (chn * CHT + (u >> 6)) * 32 + (u & 31);
            const float* p = tsrc + (size_t)pt * 3;
            rx[ps] = p[0]; ry[ps] = p[1]; rz[ps] = p[2];
        }

        // 32 tiles: per tile 1 ds_read_b128 + 2 MFMA + 32 v_min
#pragma unroll 4
        for (int t = 0; t < CHT; ++t) {
            short8 bfr = sB[t * 64 + lane];
            f32x16 a0 = __builtin_amdgcn_mfma_f32_32x32x16_bf16(
                afr[0], bfr, zero, 0, 0, 0);
            f32x16 a1 = __builtin_amdgcn_mfma_f32_32x32x16_bf16(
                afr[1], bfr, zero, 0, 0, 0);
#pragma unroll
            for (int r = 0; r < 16; ++r) {
                gm[0][r] = fminf(gm[0][r], a0[r]);
                gm[1][r] = fminf(gm[1][r], a1[r]);
            }
        }
    }

    // Epilogue: fold row-mins across the 32 target-cols (c31 lanes).
#pragma unroll
    for (int off = 1; off < 32; off <<= 1)
#pragma unroll
        for (int fr = 0; fr < 2; ++fr)
#pragma unroll
            for (int r = 0; r < 16; ++r)
                gm[fr][r] = fminf(gm[fr][r], __shfl_xor(gm[fr][r], off, 64));

    // lanes 0 and 32 hold complete mins for 2x16 disjoint rows each
    float s = 0.0f;
    if (c31 == 0) {
#pragma unroll
        for (int fr = 0; fr < 2; ++fr)
#pragma unroll
            for (int r = 0; r < 16; ++r)
                s += sqrtf(fmaxf(gm[fr][r], 1e-12f));
    }
    s += __shfl_xor(s, 32, 64);   // combine halves
    if (lane == 0) sw[wid] = s;
    __syncthreads();
    if (tid == 0)
        wsgt[bx] = sw[0]+sw[1]+sw[2]+sw[3]+sw[4]+sw[5]+sw[6]+sw[7];
}

// ---- finish: one block sums the 512 per-block partials -> out[0] ----
__global__ __launch_bounds__(TPBP) void chamfer_finish(
    const float* __restrict__ wsgt, float* __restrict__ out)
{
    __shared__ float swv[TPBP / 64];
    const int tid = threadIdx.x;

    float s = 0.0f;
#pragma unroll
    for (int r = 0; r < GRID_MAIN / TPBP; ++r)
        s += wsgt[tid + r * TPBP];

#pragma unroll
    for (int off = 32; off > 0; off >>= 1) s += __shfl_down(s, off, 64);
    const int wid = tid >> 6, lane = tid & 63;
    if (lane == 0) swv[wid] = s;
    __syncthreads();
    if (tid == 0)
        out[0] = (swv[0] + swv[1] + swv[2] + swv[3]) * (1.0f / 131072.0f);
}

extern "C" void kernel_launch(void* const* d_in, const int* in_sizes, int n_in,
                              void* d_out, int out_size, void* d_ws, size_t ws_size,
                              hipStream_t stream)
{
    const float* pred = (const float*)d_in[0];
    const float* gt   = (const float*)d_in[1];
    float* out        = (float*)d_out;
    float* wsgt       = (float*)d_ws;   // 2KB of partials; no other ws use

    chamfer_mfma<<<dim3(GRID_MAIN), dim3(TPBM), 0, stream>>>(pred, gt, wsgt);
    chamfer_finish<<<dim3(1), dim3(TPBP), 0, stream>>>(wsgt, out);
}